// Round 1
// baseline (106.615 us; speedup 1.0000x reference)
//
#include <hip/hip_runtime.h>
#include <math.h>

// ---------------------------------------------------------------------------
// TropicalMLP: h_i = logsumexp_j(x_j + w_ij) + b_i = log(sum_j e^x_j e^w_ij)+b_i
// Row-independent network: one block owns 4 batch rows, runs all 3 layers +
// 2 tropical-LNs with only __syncthreads(). Two dispatches.
// fp8 e4m3 operands (640KB/block weight stream) via mfma_f32_16x16x32_fp8_fp8.
// Scaling keeps fp8 normal-range: layer1 A = 4*exp(x) (+ln4 cancels in LN1
// median); layers2/3 A = 64*exp(y-cm) (+ln64 cancels in LN2; subtracted in
// final epilogue). B = exp(w) in [0.6,1.6] needs no scale.
// Weights pre-exp'd + permuted to MFMA-fragment order (512B-coalesced loads).
// R8: B-prefetch for each layer hoisted ABOVE the preceding barrier.
// R9: I-FOOTPRINT FIX. The two inlined, fully-unrolled 45-round bitonic
// networks were ~32KB of straight-line code (whole kernel ~45KB > 32KB L1I);
// with zero code reuse every line is a cold fetch -> all pipes idle (MfmaUtil
// 3.5%, VALUBusy 11%, HBM 1.2%). Sort rounds are now runtime loops
// (unroll-disabled) with compile-time-static v[] indexing; math identical.
// ---------------------------------------------------------------------------

typedef float v4f __attribute__((ext_vector_type(4)));

#define ELS_B 528                  // bytes per LDS A-row (16B pad: 2-way banks = free)
#define LN64f 4.1588830833596715f  // ln(64)

__device__ __forceinline__ int pk4_fp8(float a, float b, float c, float d) {
    int p = __builtin_amdgcn_cvt_pk_fp8_f32(a, b, 0, 0);      // bytes 0,1
    p = __builtin_amdgcn_cvt_pk_fp8_f32(c, d, p, 1);          // bytes 2,3
    return p;
}

// D1: exp + fp8 + fragment reorder. Global 16-col tile S, k-step t (32 k),
// lane l = q*16+r:  Ef[(S*16+t)*512 + l*8 + j] = fp8(exp(W[S*16+r][t*32+q*8+j]))
// S: 0..31 -> w1, 32..63 -> w2, 64..79 -> w3 (contiguous per layer, in bytes).
__global__ __launch_bounds__(256) void expW_frag(const float* __restrict__ w1,
                                                 const float* __restrict__ w2,
                                                 const float* __restrict__ w3,
                                                 uint8_t* __restrict__ Ef) {
    int u = blockIdx.x * 256 + threadIdx.x;          // 0..81919 (320 blocks)
    int lane = u & 63, t = (u >> 6) & 15, S = u >> 10;
    int r = lane & 15, q = lane >> 4;
    const float* w; int tile;
    if (S < 32)      { w = w1; tile = S; }
    else if (S < 64) { w = w2; tile = S - 32; }
    else             { w = w3; tile = S - 64; }
    const float* src = w + (tile * 16 + r) * 512 + t * 32 + q * 8;
    float4 a = *reinterpret_cast<const float4*>(src);
    float4 b = *reinterpret_cast<const float4*>(src + 4);
    int2 o;
    o.x = pk4_fp8(__expf(a.x), __expf(a.y), __expf(a.z), __expf(a.w));
    o.y = pk4_fp8(__expf(b.x), __expf(b.y), __expf(b.z), __expf(b.w));
    *reinterpret_cast<int2*>(Ef + u * 8) = o;
}

// Preload whole A operand (4 rows dup'd 4x in the 16-row slot) for all 16
// k-steps: 16 x ds_read_b64.
__device__ __forceinline__ void load_areg(const uint8_t* Els, int lane, long* areg) {
    const uint8_t* ap = Els + (lane & 3) * ELS_B + ((lane >> 4) & 3) * 8;
#pragma unroll
    for (int t = 0; t < 16; ++t)
        areg[t] = *reinterpret_cast<const long*>(ap + t * 32);
}

// Issue the first 8 k-steps of a layer's B stream (kept in flight across the
// following barrier / LN — this is the latency-hiding hoist).
template <int NSUB>
__device__ __forceinline__ void prefetchB(const uint8_t* __restrict__ bp,
                                          int s0, long bb[8][4]) {
#pragma unroll
    for (int p = 0; p < 8; ++p)
#pragma unroll
        for (int s = 0; s < NSUB; ++s)
            bb[p][s] = *reinterpret_cast<const long*>(bp + ((s0 + s) * 16 + p) * 512);
}

// C[16(dup rows) x NSUB*16 cols] over K=512, fp8 MFMA, consuming the
// prefetched pipe and rolling it forward (depth 8).
template <int NSUB>
__device__ __forceinline__ void gemm_body(const uint8_t* __restrict__ bp,
                                          int s0, const long* areg,
                                          long bb[8][4], v4f* acc) {
#pragma unroll
    for (int s = 0; s < NSUB; ++s) acc[s] = (v4f){0.f, 0.f, 0.f, 0.f};
#pragma unroll
    for (int t = 0; t < 16; ++t) {
        long a = areg[t];
        long bcur[NSUB];
#pragma unroll
        for (int s = 0; s < NSUB; ++s) bcur[s] = bb[t & 7][s];
        if (t < 8) {
#pragma unroll
            for (int s = 0; s < NSUB; ++s)
                bb[t & 7][s] =
                    *reinterpret_cast<const long*>(bp + ((s0 + s) * 16 + t + 8) * 512);
        }
#pragma unroll
        for (int s = 0; s < NSUB; ++s)
            acc[s] = __builtin_amdgcn_mfma_f32_16x16x32_fp8_fp8(a, bcur[s],
                                                                acc[s], 0, 0, 0);
    }
}

// Tropical-LN on one row (1 wave, lane-major): exact order stats via
// in-register bitonic (R9: compact loop form, not unrolled); relu; subtract
// rowmax; 64*exp -> fp8 into Els.
__device__ __forceinline__ void ln_row(const float* hbuf,
                                       const float* __restrict__ lw,
                                       const float* __restrict__ lb,
                                       uint8_t* Els, float* crow,
                                       int w, int lane) {
    // lw/lb loads issued FIRST so they're in flight during the whole sort.
    const float4* lw4 = reinterpret_cast<const float4*>(lw + lane * 8);
    const float4* lb4 = reinterpret_cast<const float4*>(lb + lane * 8);
    float4 wa = lw4[0], wb = lw4[1], ba = lb4[0], bbv = lb4[1];

    float h[8], v[8];
    {
        const float* hp = hbuf + w * 512 + lane * 8;
        float4 a = *reinterpret_cast<const float4*>(hp);
        float4 b = *reinterpret_cast<const float4*>(hp + 4);
        h[0] = a.x; h[1] = a.y; h[2] = a.z; h[3] = a.w;
        h[4] = b.x; h[5] = b.y; h[6] = b.z; h[7] = b.w;
#pragma unroll
        for (int j = 0; j < 8; ++j) v[j] = h[j];
    }
    // Bitonic sort of 512 values, element e = lane*8 + j, ascending.
    // Runtime k/jj loops (code-size: ~120 instrs vs ~2000 unrolled); all v[]
    // indices remain compile-time constants (runtime-indexed regs -> scratch).
#pragma clang loop unroll(disable)
    for (int k = 2; k <= 512; k <<= 1) {
#pragma clang loop unroll(disable)
        for (int jj = (k >> 1); jj > 0; jj >>= 1) {
            if (jj >= 8) {
                int lm = jj >> 3;
                bool low = ((lane & lm) == 0);
#pragma unroll
                for (int j = 0; j < 8; ++j) {
                    float pv = __shfl_xor(v[j], lm);
                    bool up = ((((lane << 3) | j) & k) == 0);
                    v[j] = (up == low) ? fminf(v[j], pv) : fmaxf(v[j], pv);
                }
            } else if (jj == 4) {
#pragma unroll
                for (int j = 0; j < 4; ++j) {
                    bool up = ((((lane << 3) | j) & k) == 0);
                    float a = v[j], c = v[j + 4];
                    float lo = fminf(a, c), hi = fmaxf(a, c);
                    v[j] = up ? lo : hi;
                    v[j + 4] = up ? hi : lo;
                }
            } else if (jj == 2) {
#pragma unroll
                for (int jb = 0; jb < 8; jb += 4)
#pragma unroll
                    for (int j0 = 0; j0 < 2; ++j0) {
                        int j = jb + j0;
                        bool up = ((((lane << 3) | j) & k) == 0);
                        float a = v[j], c = v[j + 2];
                        float lo = fminf(a, c), hi = fmaxf(a, c);
                        v[j] = up ? lo : hi;
                        v[j + 2] = up ? hi : lo;
                    }
            } else {  // jj == 1
#pragma unroll
                for (int j = 0; j < 8; j += 2) {
                    bool up = ((((lane << 3) | j) & k) == 0);
                    float a = v[j], c = v[j + 1];
                    float lo = fminf(a, c), hi = fmaxf(a, c);
                    v[j] = up ? lo : hi;
                    v[j + 1] = up ? hi : lo;
                }
            }
        }
    }
    float s127 = __shfl(v[7], 15);
    float s128 = __shfl(v[0], 16);
    float med  = __shfl(v[7], 31);
    float s383 = __shfl(v[7], 47);
    float s384 = __shfl(v[0], 48);
    float q25 = s127 + 0.75f * (s128 - s127);
    float q75 = s383 + 0.25f * (s384 - s383);
    float inv = 1.0f / fmaxf(q75 - q25, 1e-6f);

    float y[8], cm = 0.0f;                      // y >= 0 after relu
    {
        float lwv[8] = {wa.x, wa.y, wa.z, wa.w, wb.x, wb.y, wb.z, wb.w};
        float lbv[8] = {ba.x, ba.y, ba.z, ba.w, bbv.x, bbv.y, bbv.z, bbv.w};
#pragma unroll
        for (int j = 0; j < 8; ++j) {
            y[j] = fmaxf((h[j] - med) * inv * lwv[j] + lbv[j], 0.0f);
            cm = fmaxf(cm, y[j]);
        }
    }
#pragma unroll
    for (int s = 32; s > 0; s >>= 1) cm = fmaxf(cm, __shfl_xor(cm, s));
    {
        float e[8];
#pragma unroll
        for (int j = 0; j < 8; ++j) e[j] = 64.0f * __expf(y[j] - cm);
        int2 o;
        o.x = pk4_fp8(e[0], e[1], e[2], e[3]);
        o.y = pk4_fp8(e[4], e[5], e[6], e[7]);
        *reinterpret_cast<int2*>(&Els[w * ELS_B + lane * 8]) = o;
    }
    if (lane == 0) crow[w] = cm;
}

__global__ __launch_bounds__(512, 2) void fused_rows(
    const float* __restrict__ x,
    const float* __restrict__ b1,
    const float* __restrict__ ln1w, const float* __restrict__ ln1b,
    const float* __restrict__ b2,
    const float* __restrict__ ln2w, const float* __restrict__ ln2b,
    const float* __restrict__ b3,
    const uint8_t* __restrict__ Ew,
    float* __restrict__ out)
{
    __shared__ uint8_t Els[4 * ELS_B];         // fp8 activations
    __shared__ float hbuf[4 * 512];            // pre-LN layer output
    __shared__ float crow[4];                  // per-row shift (last LN)

    const int tid = threadIdx.x;
    const int lane = tid & 63;
    const int w = tid >> 6;                    // wave id 0..7
    const int r = lane & 15, q = lane >> 4;
    const int blk = blockIdx.x;                // rows 4*blk .. 4*blk+3

    const uint8_t* bp1 = Ew + lane * 8;
    const uint8_t* bp2 = bp1 + 262144;
    const uint8_t* bp3 = bp1 + 524288;

    long bb[8][4];
    long areg[16];
    v4f acc[4];

    // ---- layer-1 B prefetch in flight during the exp(x) prologue ----
    prefetchB<4>(bp1, w * 4, bb);

    // ---- phase 0: A1 = fp8(4*exp(x)) for this block's 4 rows ----
    // (+ln4 shift cancels in LN1's median subtraction; keeps fp8 normal-range)
    {
        int row = tid >> 7, col = (tid & 127) * 4;
        float4 a = *reinterpret_cast<const float4*>(x + blk * 2048 + row * 512 + col);
        *reinterpret_cast<int*>(&Els[row * ELS_B + col]) =
            pk4_fp8(4.0f * __expf(a.x), 4.0f * __expf(a.y),
                    4.0f * __expf(a.z), 4.0f * __expf(a.w));
    }
    __syncthreads();

    // ===== layer 1: wave w covers cols w*64..w*64+64 (tiles w*4..w*4+4) =====
    load_areg(Els, lane, areg);
    gemm_body<4>(bp1, w * 4, areg, bb, acc);
    if (q == 0) {
#pragma unroll
        for (int s = 0; s < 4; ++s) {
            int col = (w * 4 + s) * 16 + r;
            float bbv = b1[col];
#pragma unroll
            for (int t = 0; t < 4; ++t)
                hbuf[t * 512 + col] = __logf(acc[s][t]) + bbv;
        }
    }
    prefetchB<4>(bp2, w * 4, bb);              // layer-2 B rides over LN1
    __syncthreads();
    if (w < 4) ln_row(hbuf, ln1w, ln1b, Els, crow, w, lane);
    __syncthreads();

    // ===== layer 2 (uniform ln64 - cm1 shift absorbed by LN2's median) =====
    load_areg(Els, lane, areg);
    gemm_body<4>(bp2, w * 4, areg, bb, acc);
    if (q == 0) {
#pragma unroll
        for (int s = 0; s < 4; ++s) {
            int col = (w * 4 + s) * 16 + r;
            float bbv = b2[col];
#pragma unroll
            for (int t = 0; t < 4; ++t)
                hbuf[t * 512 + col] = __logf(acc[s][t]) + bbv;
        }
    }
    prefetchB<2>(bp3, w * 2, bb);              // layer-3 B rides over LN2
    __syncthreads();
    if (w < 4) ln_row(hbuf, ln2w, ln2b, Els, crow, w, lane);
    __syncthreads();

    // ===== layer 3 (N=256, tiles w*2..w*2+2): out = log(acc)+cm2-ln64+b3 =====
    load_areg(Els, lane, areg);
    gemm_body<2>(bp3, w * 2, areg, bb, acc);
    if (q == 0) {
#pragma unroll
        for (int s = 0; s < 2; ++s) {
            int col = (w * 2 + s) * 16 + r;
            float bbv = b3[col] - LN64f;
#pragma unroll
            for (int t = 0; t < 4; ++t)
                out[(blk * 4 + t) * 256 + col] = __logf(acc[s][t]) + crow[t] + bbv;
        }
    }
}

extern "C" void kernel_launch(void* const* d_in, const int* in_sizes, int n_in,
                              void* d_out, int out_size, void* d_ws, size_t ws_size,
                              hipStream_t stream) {
    const float* x    = (const float*)d_in[0];
    const float* w1   = (const float*)d_in[1];
    const float* b1   = (const float*)d_in[2];
    const float* ln1w = (const float*)d_in[3];
    const float* ln1b = (const float*)d_in[4];
    const float* w2   = (const float*)d_in[5];
    const float* b2   = (const float*)d_in[6];
    const float* ln2w = (const float*)d_in[7];
    const float* ln2b = (const float*)d_in[8];
    const float* w3   = (const float*)d_in[9];
    const float* b3   = (const float*)d_in[10];
    float* out = (float*)d_out;

    uint8_t* Ew = (uint8_t*)d_ws;              // 655360 B fp8 = 640 KB

    expW_frag<<<320, 256, 0, stream>>>(w1, w2, w3, Ew);
    fused_rows<<<256, 512, 0, stream>>>(x, b1, ln1w, ln1b, b2, ln2w, ln2b,
                                        b3, Ew, out);
}